// Round 1
// baseline (540.307 us; speedup 1.0000x reference)
//
#include <hip/hip_runtime.h>

typedef __attribute__((ext_vector_type(4))) float f32x4;
typedef __attribute__((ext_vector_type(8))) short bf16x8;

__device__ __forceinline__ unsigned short f2bf(float f) {
    union { float f; unsigned int u; } x; x.f = f;
    unsigned int u = x.u;
    return (unsigned short)((u + 0x7FFFu + ((u >> 16) & 1u)) >> 16);
}
__device__ __forceinline__ float bf2f(unsigned short b) {
    union { unsigned int u; float f; } x; x.u = ((unsigned int)b) << 16;
    return x.f;
}

// ---------------- prep: concat W_k|W_v and biases ----------------
__global__ void prep_wkv(const float* __restrict__ Wk, const float* __restrict__ bk,
                         const float* __restrict__ Wv, const float* __restrict__ bv,
                         float* __restrict__ Wkv, float* __restrict__ bkv) {
    int i = blockIdx.x * 256 + threadIdx.x;
    if (i < 512 * 256) Wkv[i] = (i < 256 * 256) ? Wk[i] : Wv[i - 256 * 256];
    if (i < 512) bkv[i] = (i < 256) ? bk[i] : bv[i - 256];
}

// ---------------- transpose features [48][256][2816] -> bf16 [48][2816][256] ----------------
__global__ __launch_bounds__(256) void transpose_feat(const float* __restrict__ src,
                                                      unsigned short* __restrict__ dst) {
    __shared__ float tile[32][33];
    int img = blockIdx.z;
    int p0 = blockIdx.x * 32;   // pixel
    int d0 = blockIdx.y * 32;   // channel
    int tx = threadIdx.x & 31, ty = threadIdx.x >> 5;
    const float* s = src + (size_t)img * 256 * 2816;
    unsigned short* o = dst + (size_t)img * 2816 * 256;
#pragma unroll
    for (int i = 0; i < 4; i++) tile[ty + 8 * i][tx] = s[(size_t)(d0 + ty + 8 * i) * 2816 + p0 + tx];
    __syncthreads();
#pragma unroll
    for (int i = 0; i < 4; i++) o[(size_t)(p0 + ty + 8 * i) * 256 + d0 + tx] = f2bf(tile[tx][ty + 8 * i]);
}

// ---------------- camf: project points, sample features, q_off = query + camf ----------------
__global__ __launch_bounds__(256) void camf_kernel(
    const float* __restrict__ query, const float* __restrict__ points,
    const unsigned short* __restrict__ feat_t,
    const float* __restrict__ camM, const float* __restrict__ camb,
    float* __restrict__ q_off, float* __restrict__ pxy) {
    int cid = blockIdx.x;             // cam*7200 + b*900 + k
    int cam = cid / 7200;
    int bk  = cid % 7200;             // b*900 + k
    int b   = bk / 900;

    const float* p = points + (size_t)bk * 3;
    const float* M = camM + cam * 6;
    float s0 = M[0] * p[0] + M[1] * p[1] + M[2] * p[2] + camb[cam * 2 + 0];
    float s1 = M[3] * p[0] + M[4] * p[1] + M[5] * p[2] + camb[cam * 2 + 1];
    float sig0 = 1.f / (1.f + expf(-s0));
    float sig1 = 1.f / (1.f + expf(-s1));
    float px0 = sig0 * 32.f, px1 = sig1 * 88.f;
    float gx = 2.f * px0 / 32.f - 1.f, gy = 2.f * px1 / 88.f - 1.f;
    float ix = (gx + 1.f) * 0.5f * 87.f;
    float iy = (gy + 1.f) * 0.5f * 31.f;
    float x0 = floorf(ix), y0 = floorf(iy), x1 = x0 + 1.f, y1 = y0 + 1.f;
    float wx1 = ix - x0, wx0 = x1 - ix, wy1 = iy - y0, wy0 = y1 - iy;
    float m00 = (x0 >= 0.f && x0 <= 87.f && y0 >= 0.f && y0 <= 31.f) ? 1.f : 0.f;
    float m01 = (x1 >= 0.f && x1 <= 87.f && y0 >= 0.f && y0 <= 31.f) ? 1.f : 0.f;
    float m10 = (x0 >= 0.f && x0 <= 87.f && y1 >= 0.f && y1 <= 31.f) ? 1.f : 0.f;
    float m11 = (x1 >= 0.f && x1 <= 87.f && y1 >= 0.f && y1 <= 31.f) ? 1.f : 0.f;
    float w00 = wx0 * wy0 * m00, w01 = wx1 * wy0 * m01, w10 = wx0 * wy1 * m10, w11 = wx1 * wy1 * m11;
    int xi0 = (int)fminf(fmaxf(x0, 0.f), 87.f);
    int xi1 = (int)fminf(fmaxf(x1, 0.f), 87.f);
    int yi0 = (int)fminf(fmaxf(y0, 0.f), 31.f);
    int yi1 = (int)fminf(fmaxf(y1, 0.f), 31.f);

    size_t img = (size_t)(cam * 8 + b) * 2816;
    const unsigned short* f00 = feat_t + (img + yi0 * 88 + xi0) * 256;
    const unsigned short* f01 = feat_t + (img + yi0 * 88 + xi1) * 256;
    const unsigned short* f10 = feat_t + (img + yi1 * 88 + xi0) * 256;
    const unsigned short* f11 = feat_t + (img + yi1 * 88 + xi1) * 256;

    int c = threadIdx.x;
    float val = w00 * bf2f(f00[c]) + w01 * bf2f(f01[c]) + w10 * bf2f(f10[c]) + w11 * bf2f(f11[c]);
    q_off[(size_t)cid * 256 + c] = query[(size_t)bk * 256 + c] + val;
    if (c == 0) { pxy[cid * 2 + 0] = px0; pxy[cid * 2 + 1] = px1; }
}

// ---------------- split-bf16 MFMA GEMM: C[m,n] = sum_k A[m,k]*B[n,k] + bias[n] ----------------
// A_ROW: A row-major (elem (m,k) at m*lda+k); else col-major (elem at k*lda+m).
// B always row-major [N][K] fp32. SPLIT: 3-term hi/lo split (~fp32 accuracy).
template <bool A_ROW, bool SPLIT, bool C_BF16>
__global__ __launch_bounds__(256) void gemm_bf16(
    const float* __restrict__ A, long long aBatch,
    const float* __restrict__ B, const float* __restrict__ bias,
    void* __restrict__ Cv, long long cBatch,
    int M, int N, int K, int lda) {
    __shared__ __align__(16) unsigned short Ah[64][40];
    __shared__ __align__(16) unsigned short Bh[64][40];
    __shared__ __align__(16) unsigned short Al[64][40];
    __shared__ __align__(16) unsigned short Bl[64][40];

    const int tid = threadIdx.x;
    const int m0 = blockIdx.x * 64, n0 = blockIdx.y * 64;
    const int batch = blockIdx.z;
    const float* Ab = A + (size_t)batch * aBatch;
    const int lane = tid & 63, wave = tid >> 6;
    const int wr = wave & 1, wc = wave >> 1;
    const int lrow = lane & 15, lk = lane >> 4;

    f32x4 acc[2][2] = {};

    for (int kt = 0; kt < K; kt += 32) {
        if (kt) __syncthreads();
        if (A_ROW) {
            int c4 = (tid & 7) * 4;
#pragma unroll
            for (int rep = 0; rep < 2; rep++) {
                int r = (tid >> 3) + rep * 32;
                int m = m0 + r; if (m >= M) m = M - 1;
                f32x4 v = *(const f32x4*)(Ab + (size_t)m * lda + kt + c4);
#pragma unroll
                for (int q = 0; q < 4; q++) {
                    unsigned short h = f2bf(v[q]);
                    Ah[r][c4 + q] = h;
                    if (SPLIT) Al[r][c4 + q] = f2bf(v[q] - bf2f(h));
                }
            }
        } else {
            int m_l = tid & 63;
            int m = m0 + m_l; if (m >= M) m = M - 1;
#pragma unroll
            for (int rep = 0; rep < 8; rep++) {
                int k_l = (tid >> 6) + rep * 4;
                float v = Ab[(size_t)(kt + k_l) * lda + m];
                unsigned short h = f2bf(v);
                Ah[m_l][k_l] = h;
                if (SPLIT) Al[m_l][k_l] = f2bf(v - bf2f(h));
            }
        }
        {
            int c4 = (tid & 7) * 4;
#pragma unroll
            for (int rep = 0; rep < 2; rep++) {
                int r = (tid >> 3) + rep * 32;
                f32x4 v = *(const f32x4*)(B + (size_t)(n0 + r) * K + kt + c4);
#pragma unroll
                for (int q = 0; q < 4; q++) {
                    unsigned short h = f2bf(v[q]);
                    Bh[r][c4 + q] = h;
                    if (SPLIT) Bl[r][c4 + q] = f2bf(v[q] - bf2f(h));
                }
            }
        }
        __syncthreads();

        bf16x8 a_h[2], b_h[2], a_l[2], b_l[2];
#pragma unroll
        for (int i = 0; i < 2; i++) {
            a_h[i] = *(const bf16x8*)&Ah[wr * 32 + i * 16 + lrow][lk * 8];
            b_h[i] = *(const bf16x8*)&Bh[wc * 32 + i * 16 + lrow][lk * 8];
            if (SPLIT) {
                a_l[i] = *(const bf16x8*)&Al[wr * 32 + i * 16 + lrow][lk * 8];
                b_l[i] = *(const bf16x8*)&Bl[wc * 32 + i * 16 + lrow][lk * 8];
            }
        }
#pragma unroll
        for (int i = 0; i < 2; i++)
#pragma unroll
            for (int j = 0; j < 2; j++) {
                acc[i][j] = __builtin_amdgcn_mfma_f32_16x16x32_bf16(a_h[i], b_h[j], acc[i][j], 0, 0, 0);
                if (SPLIT) {
                    acc[i][j] = __builtin_amdgcn_mfma_f32_16x16x32_bf16(a_h[i], b_l[j], acc[i][j], 0, 0, 0);
                    acc[i][j] = __builtin_amdgcn_mfma_f32_16x16x32_bf16(a_l[i], b_h[j], acc[i][j], 0, 0, 0);
                }
            }
    }

#pragma unroll
    for (int i = 0; i < 2; i++)
#pragma unroll
        for (int j = 0; j < 2; j++) {
            int n = n0 + wc * 32 + j * 16 + lrow;
            float bs = bias[n];
#pragma unroll
            for (int jj = 0; jj < 4; jj++) {
                int m = m0 + wr * 32 + i * 16 + lk * 4 + jj;
                if (m < M) {
                    float val = acc[i][j][jj] + bs;
                    if (C_BF16)
                        ((unsigned short*)Cv)[(size_t)batch * cBatch + (size_t)m * N + n] = f2bf(val);
                    else
                        ((float*)Cv)[(size_t)batch * cBatch + (size_t)m * N + n] = val;
                }
            }
        }
}

// ---------------- fused deformable attention ----------------
__global__ __launch_bounds__(64) void attn_kernel(
    const float* __restrict__ q_proj, const float* __restrict__ pxy,
    const float* __restrict__ offs, const unsigned short* __restrict__ kv_t,
    float* __restrict__ S) {
    int bid = blockIdx.x;   // b*7200 + h*900 + k
    int b = bid / 7200;
    int r = bid % 7200;
    int h = r / 900;
    int k = r % 900;
    int tid = threadIdx.x;
    int d = tid & 31, half = tid >> 5;

    float qd = q_proj[((size_t)(b * 900 + k)) * 256 + h * 32 + d];
    __shared__ float logits[24];
    float vreg[24];
    const float inv_sqrt = 0.17677669529663687f;

#pragma unroll
    for (int l = 0; l < 24; l++) {
        int cam = l >> 2, p = l & 3;
        int cid = cam * 7200 + b * 900 + k;
        float px0 = pxy[cid * 2 + 0], px1 = pxy[cid * 2 + 1];
        float o0 = offs[(size_t)cid * 64 + (h * 4 + p) * 2 + 0];
        float o1 = offs[(size_t)cid * 64 + (h * 4 + p) * 2 + 1];
        float pc0 = px0 + o0 * (1.f / 32.f);
        float pc1 = px1 + o1 * (1.f / 88.f);
        float gx = 2.f * (pc0 * (1.f / 32.f)) - 1.f;
        float gy = 2.f * (pc1 * (1.f / 88.f)) - 1.f;
        float ix = (gx + 1.f) * 0.5f * 87.f;
        float iy = (gy + 1.f) * 0.5f * 31.f;
        float x0 = floorf(ix), y0 = floorf(iy), x1 = x0 + 1.f, y1 = y0 + 1.f;
        float wx1 = ix - x0, wx0 = x1 - ix, wy1 = iy - y0, wy0 = y1 - iy;
        float m00 = (x0 >= 0.f && x0 <= 87.f && y0 >= 0.f && y0 <= 31.f) ? 1.f : 0.f;
        float m01 = (x1 >= 0.f && x1 <= 87.f && y0 >= 0.f && y0 <= 31.f) ? 1.f : 0.f;
        float m10 = (x0 >= 0.f && x0 <= 87.f && y1 >= 0.f && y1 <= 31.f) ? 1.f : 0.f;
        float m11 = (x1 >= 0.f && x1 <= 87.f && y1 >= 0.f && y1 <= 31.f) ? 1.f : 0.f;
        float w00 = wx0 * wy0 * m00, w01 = wx1 * wy0 * m01;
        float w10 = wx0 * wy1 * m10, w11 = wx1 * wy1 * m11;
        int xi0 = (int)fminf(fmaxf(x0, 0.f), 87.f);
        int xi1 = (int)fminf(fmaxf(x1, 0.f), 87.f);
        int yi0 = (int)fminf(fmaxf(y0, 0.f), 31.f);
        int yi1 = (int)fminf(fmaxf(y1, 0.f), 31.f);
        size_t img = (size_t)(cam * 8 + b) * 2816;
        int ch = half * 256 + h * 32 + d;
        float v = w00 * bf2f(kv_t[(img + yi0 * 88 + xi0) * 512 + ch])
                + w01 * bf2f(kv_t[(img + yi0 * 88 + xi1) * 512 + ch])
                + w10 * bf2f(kv_t[(img + yi1 * 88 + xi0) * 512 + ch])
                + w11 * bf2f(kv_t[(img + yi1 * 88 + xi1) * 512 + ch]);
        vreg[l] = v;
        float t = qd * v;
        t += __shfl_xor(t, 16);
        t += __shfl_xor(t, 8);
        t += __shfl_xor(t, 4);
        t += __shfl_xor(t, 2);
        t += __shfl_xor(t, 1);
        if (tid == 0) logits[l] = t * inv_sqrt;
    }
    __syncthreads();

    float mx = -1e30f;
#pragma unroll
    for (int l = 0; l < 24; l++) mx = fmaxf(mx, logits[l]);
    float ssum = 0.f;
    float at[24];
#pragma unroll
    for (int l = 0; l < 24; l++) { at[l] = expf(logits[l] - mx); ssum += at[l]; }
    float inv = 1.f / ssum;
    if (half == 1) {
        float acc = 0.f;
#pragma unroll
        for (int l = 0; l < 24; l++) acc += at[l] * inv * vreg[l];
        S[(size_t)b * 230400 + (size_t)h * 28800 + k * 32 + d] = acc;
    }
}

extern "C" void kernel_launch(void* const* d_in, const int* in_sizes, int n_in,
                              void* d_out, int out_size, void* d_ws, size_t ws_size,
                              hipStream_t stream) {
    const float* query    = (const float*)d_in[0];
    const float* points   = (const float*)d_in[1];
    const float* features = (const float*)d_in[2];
    const float* camM     = (const float*)d_in[3];
    const float* camb     = (const float*)d_in[4];
    const float* W_off    = (const float*)d_in[5];
    const float* b_off    = (const float*)d_in[6];
    const float* W_q      = (const float*)d_in[7];
    const float* b_q      = (const float*)d_in[8];
    const float* W_k      = (const float*)d_in[9];
    const float* b_k      = (const float*)d_in[10];
    const float* W_v      = (const float*)d_in[11];
    const float* b_v      = (const float*)d_in[12];
    const float* W_o      = (const float*)d_in[13];
    const float* b_o      = (const float*)d_in[14];

    char* ws = (char*)d_ws;
    unsigned short* feat_t = (unsigned short*)ws; ws += 69206016;   // [48][2816][256] bf16
    unsigned short* kv_t   = (unsigned short*)ws; ws += 138412032;  // [48][2816][512] bf16
    float* q_off  = (float*)ws; ws += 44236800;                     // [43200][256]
    float* offs   = (float*)ws; ws += 11059200;                     // [43200][64]
    float* pxy    = (float*)ws; ws += 345600;                       // [43200][2]
    float* q_proj = (float*)ws; ws += 7372800;                      // [7200][256]
    float* S      = (float*)ws; ws += 7372800;                      // [8][230400] scrambled
    float* Wkv    = (float*)ws; ws += 524288;                       // [512][256]
    float* bkv    = (float*)ws; ws += 2048;                         // [512]

    prep_wkv<<<512, 256, 0, stream>>>(W_k, b_k, W_v, b_v, Wkv, bkv);
    transpose_feat<<<dim3(88, 8, 48), 256, 0, stream>>>(features, feat_t);
    camf_kernel<<<43200, 256, 0, stream>>>(query, points, feat_t, camM, camb, q_off, pxy);
    // offsets = q_off @ W_off^T + b_off : [43200 x 64]
    gemm_bf16<true, true, false><<<dim3(675, 1, 1), 256, 0, stream>>>(
        q_off, 0, W_off, b_off, offs, 0, 43200, 64, 256, 256);
    // kv_t = per-image F^T @ Wkv^T + bkv : 48 x [2816 x 512], bf16 out
    gemm_bf16<false, true, true><<<dim3(44, 8, 48), 256, 0, stream>>>(
        features, 720896LL, Wkv, bkv, kv_t, 1441792LL, 2816, 512, 256, 2816);
    // q_proj = query @ W_q^T + b_q : [7200 x 256]
    gemm_bf16<true, true, false><<<dim3(113, 4, 1), 256, 0, stream>>>(
        query, 0, W_q, b_q, q_proj, 0, 7200, 256, 256, 256);
    attn_kernel<<<57600, 64, 0, stream>>>(q_proj, pxy, offs, kv_t, S);
    // out = S @ W_o^T + b_o : [7200 x 256]
    gemm_bf16<true, true, false><<<dim3(113, 4, 1), 256, 0, stream>>>(
        S, 0, W_o, b_o, d_out, 0, 7200, 256, 256, 256);
}

// Round 2
// 402.942 us; speedup vs baseline: 1.3409x; 1.3409x over previous
//
#include <hip/hip_runtime.h>

typedef __attribute__((ext_vector_type(4))) float f32x4;
typedef __attribute__((ext_vector_type(8))) short bf16x8;

__device__ __forceinline__ unsigned short f2bf(float f) {
    union { float f; unsigned int u; } x; x.f = f;
    unsigned int u = x.u;
    return (unsigned short)((u + 0x7FFFu + ((u >> 16) & 1u)) >> 16);
}
__device__ __forceinline__ float bf2f(unsigned short b) {
    union { unsigned int u; float f; } x; x.u = ((unsigned int)b) << 16;
    return x.f;
}

// ---------------- prep: concat W_k|W_v (bf16) and biases ----------------
__global__ void prep_wkv(const float* __restrict__ Wk, const float* __restrict__ bk,
                         const float* __restrict__ Wv, const float* __restrict__ bv,
                         unsigned short* __restrict__ Wkv, float* __restrict__ bkv) {
    int i = blockIdx.x * 256 + threadIdx.x;
    if (i < 512 * 256) Wkv[i] = f2bf((i < 256 * 256) ? Wk[i] : Wv[i - 256 * 256]);
    if (i < 512) bkv[i] = (i < 256) ? bk[i] : bv[i - 256];
}

// ---------------- transpose features [48][256][2816] -> bf16 [48][2816][256] ----------------
__global__ __launch_bounds__(256) void transpose_feat(const float* __restrict__ src,
                                                      unsigned short* __restrict__ dst) {
    __shared__ float tile[32][33];
    int img = blockIdx.z;
    int p0 = blockIdx.x * 32;   // pixel
    int d0 = blockIdx.y * 32;   // channel
    int tx = threadIdx.x & 31, ty = threadIdx.x >> 5;
    const float* s = src + (size_t)img * 256 * 2816;
    unsigned short* o = dst + (size_t)img * 2816 * 256;
#pragma unroll
    for (int i = 0; i < 4; i++) tile[ty + 8 * i][tx] = s[(size_t)(d0 + ty + 8 * i) * 2816 + p0 + tx];
    __syncthreads();
#pragma unroll
    for (int i = 0; i < 4; i++) o[(size_t)(p0 + ty + 8 * i) * 256 + d0 + tx] = f2bf(tile[tx][ty + 8 * i]);
}

// ---------------- camf: project points, sample features, q_off = query + camf ----------------
__global__ __launch_bounds__(256) void camf_kernel(
    const float* __restrict__ query, const float* __restrict__ points,
    const unsigned short* __restrict__ feat_t,
    const float* __restrict__ camM, const float* __restrict__ camb,
    float* __restrict__ q_off, float* __restrict__ pxy) {
    int cid = blockIdx.x;             // cam*7200 + b*900 + k
    int cam = cid / 7200;
    int bk  = cid % 7200;             // b*900 + k
    int b   = bk / 900;

    const float* p = points + (size_t)bk * 3;
    const float* M = camM + cam * 6;
    float s0 = M[0] * p[0] + M[1] * p[1] + M[2] * p[2] + camb[cam * 2 + 0];
    float s1 = M[3] * p[0] + M[4] * p[1] + M[5] * p[2] + camb[cam * 2 + 1];
    float sig0 = 1.f / (1.f + expf(-s0));
    float sig1 = 1.f / (1.f + expf(-s1));
    float px0 = sig0 * 32.f, px1 = sig1 * 88.f;
    float gx = 2.f * px0 / 32.f - 1.f, gy = 2.f * px1 / 88.f - 1.f;
    float ix = (gx + 1.f) * 0.5f * 87.f;
    float iy = (gy + 1.f) * 0.5f * 31.f;
    float x0 = floorf(ix), y0 = floorf(iy), x1 = x0 + 1.f, y1 = y0 + 1.f;
    float wx1 = ix - x0, wx0 = x1 - ix, wy1 = iy - y0, wy0 = y1 - iy;
    float m00 = (x0 >= 0.f && x0 <= 87.f && y0 >= 0.f && y0 <= 31.f) ? 1.f : 0.f;
    float m01 = (x1 >= 0.f && x1 <= 87.f && y0 >= 0.f && y0 <= 31.f) ? 1.f : 0.f;
    float m10 = (x0 >= 0.f && x0 <= 87.f && y1 >= 0.f && y1 <= 31.f) ? 1.f : 0.f;
    float m11 = (x1 >= 0.f && x1 <= 87.f && y1 >= 0.f && y1 <= 31.f) ? 1.f : 0.f;
    float w00 = wx0 * wy0 * m00, w01 = wx1 * wy0 * m01, w10 = wx0 * wy1 * m10, w11 = wx1 * wy1 * m11;
    int xi0 = (int)fminf(fmaxf(x0, 0.f), 87.f);
    int xi1 = (int)fminf(fmaxf(x1, 0.f), 87.f);
    int yi0 = (int)fminf(fmaxf(y0, 0.f), 31.f);
    int yi1 = (int)fminf(fmaxf(y1, 0.f), 31.f);

    size_t img = (size_t)(cam * 8 + b) * 2816;
    const unsigned short* f00 = feat_t + (img + yi0 * 88 + xi0) * 256;
    const unsigned short* f01 = feat_t + (img + yi0 * 88 + xi1) * 256;
    const unsigned short* f10 = feat_t + (img + yi1 * 88 + xi0) * 256;
    const unsigned short* f11 = feat_t + (img + yi1 * 88 + xi1) * 256;

    int c = threadIdx.x;
    float val = w00 * bf2f(f00[c]) + w01 * bf2f(f01[c]) + w10 * bf2f(f10[c]) + w11 * bf2f(f11[c]);
    q_off[(size_t)cid * 256 + c] = query[(size_t)bk * 256 + c] + val;
    if (c == 0) { pxy[cid * 2 + 0] = px0; pxy[cid * 2 + 1] = px1; }
}

// ---------------- kv projection: flat bf16 GEMM, m97 structure ----------------
// C[135168][512] = A[135168][256] @ B[512][256]^T + bias  (all bf16 in, bf16 out)
__global__ __launch_bounds__(256) void gemm_kv(
    const unsigned short* __restrict__ A,
    const unsigned short* __restrict__ B,
    const float* __restrict__ bias,
    unsigned short* __restrict__ C) {
    __shared__ __align__(16) unsigned short Al[128 * 32];
    __shared__ __align__(16) unsigned short Bl[128 * 32];
    const int tid = threadIdx.x;
    const int lane = tid & 63, wave = tid >> 6;
    const int wr = wave & 1, wc = wave >> 1;
    const int lrow = lane & 15, lk = lane >> 4;
    const int m0 = blockIdx.x * 128, n0 = blockIdx.y * 128;

    const int srow = lane >> 2;        // 0..15
    const int skk  = (lane & 3) * 8;   // 0,8,16,24

    f32x4 acc[4][4] = {};

    for (int kt = 0; kt < 256; kt += 32) {
        if (kt) __syncthreads();
#pragma unroll
        for (int cc = 0; cc < 2; ++cc) {
            int c = wave * 2 + cc;
            const unsigned short* ga = A + (size_t)(m0 + c * 16 + srow) * 256 + kt + skk;
            __builtin_amdgcn_global_load_lds(
                (const __attribute__((address_space(1))) unsigned int*)ga,
                (__attribute__((address_space(3))) unsigned int*)&Al[c * 512], 16, 0, 0);
            const unsigned short* gb = B + (size_t)(n0 + c * 16 + srow) * 256 + kt + skk;
            __builtin_amdgcn_global_load_lds(
                (const __attribute__((address_space(1))) unsigned int*)gb,
                (__attribute__((address_space(3))) unsigned int*)&Bl[c * 512], 16, 0, 0);
        }
        __syncthreads();
        bf16x8 af[4], bfr[4];
#pragma unroll
        for (int i = 0; i < 4; ++i) {
            af[i]  = *(const bf16x8*)&Al[(wr * 64 + i * 16 + lrow) * 32 + lk * 8];
            bfr[i] = *(const bf16x8*)&Bl[(wc * 64 + i * 16 + lrow) * 32 + lk * 8];
        }
#pragma unroll
        for (int i = 0; i < 4; ++i)
#pragma unroll
            for (int j = 0; j < 4; ++j)
                acc[i][j] = __builtin_amdgcn_mfma_f32_16x16x32_bf16(af[i], bfr[j], acc[i][j], 0, 0, 0);
    }

#pragma unroll
    for (int j = 0; j < 4; ++j) {
        int n = n0 + wc * 64 + j * 16 + lrow;
        float bs = bias[n];
#pragma unroll
        for (int i = 0; i < 4; ++i)
#pragma unroll
            for (int jj = 0; jj < 4; ++jj) {
                int m = m0 + wr * 64 + i * 16 + lk * 4 + jj;
                C[(size_t)m * 512 + n] = f2bf(acc[i][j][jj] + bs);
            }
    }
}

// ---------------- split-bf16 MFMA GEMM (fp32 A/B in): C = A@B^T + bias ----------------
template <bool SPLIT, bool C_BF16>
__global__ __launch_bounds__(256) void gemm_bf16(
    const float* __restrict__ A, long long aBatch,
    const float* __restrict__ B, const float* __restrict__ bias,
    void* __restrict__ Cv, long long cBatch,
    int M, int N, int K, int lda) {
    __shared__ __align__(16) unsigned short Ah[64][40];
    __shared__ __align__(16) unsigned short Bh[64][40];
    __shared__ __align__(16) unsigned short Al[64][40];
    __shared__ __align__(16) unsigned short Bl[64][40];

    const int tid = threadIdx.x;
    const int m0 = blockIdx.x * 64, n0 = blockIdx.y * 64;
    const int batch = blockIdx.z;
    const float* Ab = A + (size_t)batch * aBatch;
    const int lane = tid & 63, wave = tid >> 6;
    const int wr = wave & 1, wc = wave >> 1;
    const int lrow = lane & 15, lk = lane >> 4;

    f32x4 acc[2][2] = {};

    for (int kt = 0; kt < K; kt += 32) {
        if (kt) __syncthreads();
        {
            int c4 = (tid & 7) * 4;
#pragma unroll
            for (int rep = 0; rep < 2; rep++) {
                int r = (tid >> 3) + rep * 32;
                int m = m0 + r; if (m >= M) m = M - 1;
                f32x4 v = *(const f32x4*)(Ab + (size_t)m * lda + kt + c4);
#pragma unroll
                for (int q = 0; q < 4; q++) {
                    unsigned short h = f2bf(v[q]);
                    Ah[r][c4 + q] = h;
                    if (SPLIT) Al[r][c4 + q] = f2bf(v[q] - bf2f(h));
                }
            }
        }
        {
            int c4 = (tid & 7) * 4;
#pragma unroll
            for (int rep = 0; rep < 2; rep++) {
                int r = (tid >> 3) + rep * 32;
                f32x4 v = *(const f32x4*)(B + (size_t)(n0 + r) * K + kt + c4);
#pragma unroll
                for (int q = 0; q < 4; q++) {
                    unsigned short h = f2bf(v[q]);
                    Bh[r][c4 + q] = h;
                    if (SPLIT) Bl[r][c4 + q] = f2bf(v[q] - bf2f(h));
                }
            }
        }
        __syncthreads();

        bf16x8 a_h[2], b_h[2], a_l[2], b_l[2];
#pragma unroll
        for (int i = 0; i < 2; i++) {
            a_h[i] = *(const bf16x8*)&Ah[wr * 32 + i * 16 + lrow][lk * 8];
            b_h[i] = *(const bf16x8*)&Bh[wc * 32 + i * 16 + lrow][lk * 8];
            if (SPLIT) {
                a_l[i] = *(const bf16x8*)&Al[wr * 32 + i * 16 + lrow][lk * 8];
                b_l[i] = *(const bf16x8*)&Bl[wc * 32 + i * 16 + lrow][lk * 8];
            }
        }
#pragma unroll
        for (int i = 0; i < 2; i++)
#pragma unroll
            for (int j = 0; j < 2; j++) {
                acc[i][j] = __builtin_amdgcn_mfma_f32_16x16x32_bf16(a_h[i], b_h[j], acc[i][j], 0, 0, 0);
                if (SPLIT) {
                    acc[i][j] = __builtin_amdgcn_mfma_f32_16x16x32_bf16(a_h[i], b_l[j], acc[i][j], 0, 0, 0);
                    acc[i][j] = __builtin_amdgcn_mfma_f32_16x16x32_bf16(a_l[i], b_h[j], acc[i][j], 0, 0, 0);
                }
            }
    }

#pragma unroll
    for (int i = 0; i < 2; i++)
#pragma unroll
        for (int j = 0; j < 2; j++) {
            int n = n0 + wc * 32 + j * 16 + lrow;
            float bs = bias[n];
#pragma unroll
            for (int jj = 0; jj < 4; jj++) {
                int m = m0 + wr * 32 + i * 16 + lk * 4 + jj;
                if (m < M) {
                    float val = acc[i][j][jj] + bs;
                    if (C_BF16)
                        ((unsigned short*)Cv)[(size_t)batch * cBatch + (size_t)m * N + n] = f2bf(val);
                    else
                        ((float*)Cv)[(size_t)batch * cBatch + (size_t)m * N + n] = val;
                }
            }
        }
}

// ---------------- fused deformable attention ----------------
__global__ __launch_bounds__(64) void attn_kernel(
    const float* __restrict__ q_proj, const float* __restrict__ pxy,
    const float* __restrict__ offs, const unsigned short* __restrict__ kv_t,
    float* __restrict__ S) {
    int bid = blockIdx.x;   // b*7200 + h*900 + k
    int b = bid / 7200;
    int r = bid % 7200;
    int h = r / 900;
    int k = r % 900;
    int tid = threadIdx.x;
    int d = tid & 31, half = tid >> 5;

    float qd = q_proj[((size_t)(b * 900 + k)) * 256 + h * 32 + d];
    __shared__ float logits[24];
    float vreg[24];
    const float inv_sqrt = 0.17677669529663687f;

#pragma unroll
    for (int l = 0; l < 24; l++) {
        int cam = l >> 2, p = l & 3;
        int cid = cam * 7200 + b * 900 + k;
        float px0 = pxy[cid * 2 + 0], px1 = pxy[cid * 2 + 1];
        float o0 = offs[(size_t)cid * 64 + (h * 4 + p) * 2 + 0];
        float o1 = offs[(size_t)cid * 64 + (h * 4 + p) * 2 + 1];
        float pc0 = px0 + o0 * (1.f / 32.f);
        float pc1 = px1 + o1 * (1.f / 88.f);
        float gx = 2.f * (pc0 * (1.f / 32.f)) - 1.f;
        float gy = 2.f * (pc1 * (1.f / 88.f)) - 1.f;
        float ix = (gx + 1.f) * 0.5f * 87.f;
        float iy = (gy + 1.f) * 0.5f * 31.f;
        float x0 = floorf(ix), y0 = floorf(iy), x1 = x0 + 1.f, y1 = y0 + 1.f;
        float wx1 = ix - x0, wx0 = x1 - ix, wy1 = iy - y0, wy0 = y1 - iy;
        float m00 = (x0 >= 0.f && x0 <= 87.f && y0 >= 0.f && y0 <= 31.f) ? 1.f : 0.f;
        float m01 = (x1 >= 0.f && x1 <= 87.f && y0 >= 0.f && y0 <= 31.f) ? 1.f : 0.f;
        float m10 = (x0 >= 0.f && x0 <= 87.f && y1 >= 0.f && y1 <= 31.f) ? 1.f : 0.f;
        float m11 = (x1 >= 0.f && x1 <= 87.f && y1 >= 0.f && y1 <= 31.f) ? 1.f : 0.f;
        float w00 = wx0 * wy0 * m00, w01 = wx1 * wy0 * m01;
        float w10 = wx0 * wy1 * m10, w11 = wx1 * wy1 * m11;
        int xi0 = (int)fminf(fmaxf(x0, 0.f), 87.f);
        int xi1 = (int)fminf(fmaxf(x1, 0.f), 87.f);
        int yi0 = (int)fminf(fmaxf(y0, 0.f), 31.f);
        int yi1 = (int)fminf(fmaxf(y1, 0.f), 31.f);
        size_t img = (size_t)(cam * 8 + b) * 2816;
        int ch = half * 256 + h * 32 + d;
        float v = w00 * bf2f(kv_t[(img + yi0 * 88 + xi0) * 512 + ch])
                + w01 * bf2f(kv_t[(img + yi0 * 88 + xi1) * 512 + ch])
                + w10 * bf2f(kv_t[(img + yi1 * 88 + xi0) * 512 + ch])
                + w11 * bf2f(kv_t[(img + yi1 * 88 + xi1) * 512 + ch]);
        vreg[l] = v;
        float t = qd * v;
        t += __shfl_xor(t, 16);
        t += __shfl_xor(t, 8);
        t += __shfl_xor(t, 4);
        t += __shfl_xor(t, 2);
        t += __shfl_xor(t, 1);
        if (tid == 0) logits[l] = t * inv_sqrt;
    }
    __syncthreads();

    float mx = -1e30f;
#pragma unroll
    for (int l = 0; l < 24; l++) mx = fmaxf(mx, logits[l]);
    float ssum = 0.f;
    float at[24];
#pragma unroll
    for (int l = 0; l < 24; l++) { at[l] = expf(logits[l] - mx); ssum += at[l]; }
    float inv = 1.f / ssum;
    if (half == 1) {
        float acc = 0.f;
#pragma unroll
        for (int l = 0; l < 24; l++) acc += at[l] * inv * vreg[l];
        S[(size_t)b * 230400 + (size_t)h * 28800 + k * 32 + d] = acc;
    }
}

extern "C" void kernel_launch(void* const* d_in, const int* in_sizes, int n_in,
                              void* d_out, int out_size, void* d_ws, size_t ws_size,
                              hipStream_t stream) {
    const float* query    = (const float*)d_in[0];
    const float* points   = (const float*)d_in[1];
    const float* features = (const float*)d_in[2];
    const float* camM     = (const float*)d_in[3];
    const float* camb     = (const float*)d_in[4];
    const float* W_off    = (const float*)d_in[5];
    const float* b_off    = (const float*)d_in[6];
    const float* W_q      = (const float*)d_in[7];
    const float* b_q      = (const float*)d_in[8];
    const float* W_k      = (const float*)d_in[9];
    const float* b_k      = (const float*)d_in[10];
    const float* W_v      = (const float*)d_in[11];
    const float* b_v      = (const float*)d_in[12];
    const float* W_o      = (const float*)d_in[13];
    const float* b_o      = (const float*)d_in[14];

    char* ws = (char*)d_ws;
    unsigned short* feat_t = (unsigned short*)ws; ws += 69206016;   // [48][2816][256] bf16
    unsigned short* kv_t   = (unsigned short*)ws; ws += 138412032;  // [48][2816][512] bf16
    float* q_off  = (float*)ws; ws += 44236800;                     // [43200][256]
    float* offs   = (float*)ws; ws += 11059200;                     // [43200][64]
    float* pxy    = (float*)ws; ws += 345600;                       // [43200][2]
    float* q_proj = (float*)ws; ws += 7372800;                      // [7200][256]
    float* S      = (float*)ws; ws += 7372800;                      // [8][230400] scrambled
    unsigned short* Wkv = (unsigned short*)ws; ws += 524288;        // [512][256] bf16
    float* bkv    = (float*)ws; ws += 2048;                         // [512]

    prep_wkv<<<512, 256, 0, stream>>>(W_k, b_k, W_v, b_v, Wkv, bkv);
    transpose_feat<<<dim3(88, 8, 48), 256, 0, stream>>>(features, feat_t);
    camf_kernel<<<43200, 256, 0, stream>>>(query, points, feat_t, camM, camb, q_off, pxy);
    // offsets = q_off @ W_off^T + b_off : [43200 x 64]
    gemm_bf16<true, false><<<dim3(675, 1, 1), 256, 0, stream>>>(
        q_off, 0, W_off, b_off, offs, 0, 43200, 64, 256, 256);
    // kv_t = feat_t @ Wkv^T + bkv : one flat GEMM [135168 x 512], bf16 out
    gemm_kv<<<dim3(1056, 4), 256, 0, stream>>>(feat_t, Wkv, bkv, kv_t);
    // q_proj = query @ W_q^T + b_q : [7200 x 256]
    gemm_bf16<true, false><<<dim3(113, 4, 1), 256, 0, stream>>>(
        query, 0, W_q, b_q, q_proj, 0, 7200, 256, 256, 256);
    attn_kernel<<<57600, 64, 0, stream>>>(q_proj, pxy, offs, kv_t, S);
    // out = S @ W_o^T + b_o : [7200 x 256]
    gemm_bf16<true, false><<<dim3(113, 4, 1), 256, 0, stream>>>(
        S, 0, W_o, b_o, d_out, 0, 7200, 256, 256, 256);
}

// Round 3
// 306.585 us; speedup vs baseline: 1.7623x; 1.3143x over previous
//
#include <hip/hip_runtime.h>

typedef __attribute__((ext_vector_type(4))) float f32x4;
typedef __attribute__((ext_vector_type(8))) short bf16x8;

__device__ __forceinline__ unsigned short f2bf(float f) {
    union { float f; unsigned int u; } x; x.f = f;
    unsigned int u = x.u;
    return (unsigned short)((u + 0x7FFFu + ((u >> 16) & 1u)) >> 16);
}
__device__ __forceinline__ float bf2f(unsigned short b) {
    union { unsigned int u; float f; } x; x.u = ((unsigned int)b) << 16;
    return x.f;
}

// ---------------- prep: concat W_k|W_v (bf16) and biases ----------------
__global__ void prep_wkv(const float* __restrict__ Wk, const float* __restrict__ bk,
                         const float* __restrict__ Wv, const float* __restrict__ bv,
                         unsigned short* __restrict__ Wkv, float* __restrict__ bkv) {
    int i = blockIdx.x * 256 + threadIdx.x;
    if (i < 512 * 256) Wkv[i] = f2bf((i < 256 * 256) ? Wk[i] : Wv[i - 256 * 256]);
    if (i < 512) bkv[i] = (i < 256) ? bk[i] : bv[i - 256];
}

// ---------------- transpose features [48][256][2816] -> bf16 [48][2816][256] ----------------
__global__ __launch_bounds__(256) void transpose_feat(const float* __restrict__ src,
                                                      unsigned short* __restrict__ dst) {
    __shared__ float tile[32][33];
    int img = blockIdx.z;
    int p0 = blockIdx.x * 32;   // pixel
    int d0 = blockIdx.y * 32;   // channel
    int tx = threadIdx.x & 31, ty = threadIdx.x >> 5;
    const float* s = src + (size_t)img * 256 * 2816;
    unsigned short* o = dst + (size_t)img * 2816 * 256;
#pragma unroll
    for (int i = 0; i < 4; i++) tile[ty + 8 * i][tx] = s[(size_t)(d0 + ty + 8 * i) * 2816 + p0 + tx];
    __syncthreads();
#pragma unroll
    for (int i = 0; i < 4; i++) o[(size_t)(p0 + ty + 8 * i) * 256 + d0 + tx] = f2bf(tile[tx][ty + 8 * i]);
}

// ---------------- camf: project points, sample features, q_off = query + camf ----------------
__global__ __launch_bounds__(256) void camf_kernel(
    const float* __restrict__ query, const float* __restrict__ points,
    const unsigned short* __restrict__ feat_t,
    const float* __restrict__ camM, const float* __restrict__ camb,
    float* __restrict__ q_off, float* __restrict__ pxy) {
    int cid = blockIdx.x;             // cam*7200 + b*900 + k
    int cam = cid / 7200;
    int bk  = cid % 7200;             // b*900 + k
    int b   = bk / 900;

    const float* p = points + (size_t)bk * 3;
    const float* M = camM + cam * 6;
    float s0 = M[0] * p[0] + M[1] * p[1] + M[2] * p[2] + camb[cam * 2 + 0];
    float s1 = M[3] * p[0] + M[4] * p[1] + M[5] * p[2] + camb[cam * 2 + 1];
    float sig0 = 1.f / (1.f + expf(-s0));
    float sig1 = 1.f / (1.f + expf(-s1));
    float px0 = sig0 * 32.f, px1 = sig1 * 88.f;
    float gx = 2.f * px0 / 32.f - 1.f, gy = 2.f * px1 / 88.f - 1.f;
    float ix = (gx + 1.f) * 0.5f * 87.f;
    float iy = (gy + 1.f) * 0.5f * 31.f;
    float x0 = floorf(ix), y0 = floorf(iy), x1 = x0 + 1.f, y1 = y0 + 1.f;
    float wx1 = ix - x0, wx0 = x1 - ix, wy1 = iy - y0, wy0 = y1 - iy;
    float m00 = (x0 >= 0.f && x0 <= 87.f && y0 >= 0.f && y0 <= 31.f) ? 1.f : 0.f;
    float m01 = (x1 >= 0.f && x1 <= 87.f && y0 >= 0.f && y0 <= 31.f) ? 1.f : 0.f;
    float m10 = (x0 >= 0.f && x0 <= 87.f && y1 >= 0.f && y1 <= 31.f) ? 1.f : 0.f;
    float m11 = (x1 >= 0.f && x1 <= 87.f && y1 >= 0.f && y1 <= 31.f) ? 1.f : 0.f;
    float w00 = wx0 * wy0 * m00, w01 = wx1 * wy0 * m01, w10 = wx0 * wy1 * m10, w11 = wx1 * wy1 * m11;
    int xi0 = (int)fminf(fmaxf(x0, 0.f), 87.f);
    int xi1 = (int)fminf(fmaxf(x1, 0.f), 87.f);
    int yi0 = (int)fminf(fmaxf(y0, 0.f), 31.f);
    int yi1 = (int)fminf(fmaxf(y1, 0.f), 31.f);

    size_t img = (size_t)(cam * 8 + b) * 2816;
    const unsigned short* f00 = feat_t + (img + yi0 * 88 + xi0) * 256;
    const unsigned short* f01 = feat_t + (img + yi0 * 88 + xi1) * 256;
    const unsigned short* f10 = feat_t + (img + yi1 * 88 + xi0) * 256;
    const unsigned short* f11 = feat_t + (img + yi1 * 88 + xi1) * 256;

    int c = threadIdx.x;
    float val = w00 * bf2f(f00[c]) + w01 * bf2f(f01[c]) + w10 * bf2f(f10[c]) + w11 * bf2f(f11[c]);
    q_off[(size_t)cid * 256 + c] = query[(size_t)bk * 256 + c] + val;
    if (c == 0) { pxy[cid * 2 + 0] = px0; pxy[cid * 2 + 1] = px1; }
}

// ---------------- kv projection: flat bf16 GEMM, m97 structure ----------------
// C[135168][512] = A[135168][256] @ B[512][256]^T + bias  (all bf16 in, bf16 out)
__global__ __launch_bounds__(256) void gemm_kv(
    const unsigned short* __restrict__ A,
    const unsigned short* __restrict__ B,
    const float* __restrict__ bias,
    unsigned short* __restrict__ C) {
    __shared__ __align__(16) unsigned short Al[128 * 32];
    __shared__ __align__(16) unsigned short Bl[128 * 32];
    const int tid = threadIdx.x;
    const int lane = tid & 63, wave = tid >> 6;
    const int wr = wave & 1, wc = wave >> 1;
    const int lrow = lane & 15, lk = lane >> 4;
    const int m0 = blockIdx.x * 128, n0 = blockIdx.y * 128;

    const int srow = lane >> 2;        // 0..15
    const int skk  = (lane & 3) * 8;   // 0,8,16,24

    f32x4 acc[4][4] = {};

    for (int kt = 0; kt < 256; kt += 32) {
        if (kt) __syncthreads();
#pragma unroll
        for (int cc = 0; cc < 2; ++cc) {
            int c = wave * 2 + cc;
            const unsigned short* ga = A + (size_t)(m0 + c * 16 + srow) * 256 + kt + skk;
            __builtin_amdgcn_global_load_lds(
                (const __attribute__((address_space(1))) unsigned int*)ga,
                (__attribute__((address_space(3))) unsigned int*)&Al[c * 512], 16, 0, 0);
            const unsigned short* gb = B + (size_t)(n0 + c * 16 + srow) * 256 + kt + skk;
            __builtin_amdgcn_global_load_lds(
                (const __attribute__((address_space(1))) unsigned int*)gb,
                (__attribute__((address_space(3))) unsigned int*)&Bl[c * 512], 16, 0, 0);
        }
        __syncthreads();
        bf16x8 af[4], bfr[4];
#pragma unroll
        for (int i = 0; i < 4; ++i) {
            af[i]  = *(const bf16x8*)&Al[(wr * 64 + i * 16 + lrow) * 32 + lk * 8];
            bfr[i] = *(const bf16x8*)&Bl[(wc * 64 + i * 16 + lrow) * 32 + lk * 8];
        }
#pragma unroll
        for (int i = 0; i < 4; ++i)
#pragma unroll
            for (int j = 0; j < 4; ++j)
                acc[i][j] = __builtin_amdgcn_mfma_f32_16x16x32_bf16(af[i], bfr[j], acc[i][j], 0, 0, 0);
    }

#pragma unroll
    for (int j = 0; j < 4; ++j) {
        int n = n0 + wc * 64 + j * 16 + lrow;
        float bs = bias[n];
#pragma unroll
        for (int i = 0; i < 4; ++i)
#pragma unroll
            for (int jj = 0; jj < 4; ++jj) {
                int m = m0 + wr * 64 + i * 16 + lk * 4 + jj;
                C[(size_t)m * 512 + n] = f2bf(acc[i][j][jj] + bs);
            }
    }
}

// ---------------- split-bf16 MFMA GEMM (fp32 A/B in): C = A@B^T + bias ----------------
template <bool SPLIT, bool C_BF16>
__global__ __launch_bounds__(256) void gemm_bf16(
    const float* __restrict__ A, long long aBatch,
    const float* __restrict__ B, const float* __restrict__ bias,
    void* __restrict__ Cv, long long cBatch,
    int M, int N, int K, int lda) {
    __shared__ __align__(16) unsigned short Ah[64][40];
    __shared__ __align__(16) unsigned short Bh[64][40];
    __shared__ __align__(16) unsigned short Al[64][40];
    __shared__ __align__(16) unsigned short Bl[64][40];

    const int tid = threadIdx.x;
    const int m0 = blockIdx.x * 64, n0 = blockIdx.y * 64;
    const int batch = blockIdx.z;
    const float* Ab = A + (size_t)batch * aBatch;
    const int lane = tid & 63, wave = tid >> 6;
    const int wr = wave & 1, wc = wave >> 1;
    const int lrow = lane & 15, lk = lane >> 4;

    f32x4 acc[2][2] = {};

    for (int kt = 0; kt < K; kt += 32) {
        if (kt) __syncthreads();
        {
            int c4 = (tid & 7) * 4;
#pragma unroll
            for (int rep = 0; rep < 2; rep++) {
                int r = (tid >> 3) + rep * 32;
                int m = m0 + r; if (m >= M) m = M - 1;
                f32x4 v = *(const f32x4*)(Ab + (size_t)m * lda + kt + c4);
#pragma unroll
                for (int q = 0; q < 4; q++) {
                    unsigned short h = f2bf(v[q]);
                    Ah[r][c4 + q] = h;
                    if (SPLIT) Al[r][c4 + q] = f2bf(v[q] - bf2f(h));
                }
            }
        }
        {
            int c4 = (tid & 7) * 4;
#pragma unroll
            for (int rep = 0; rep < 2; rep++) {
                int r = (tid >> 3) + rep * 32;
                f32x4 v = *(const f32x4*)(B + (size_t)(n0 + r) * K + kt + c4);
#pragma unroll
                for (int q = 0; q < 4; q++) {
                    unsigned short h = f2bf(v[q]);
                    Bh[r][c4 + q] = h;
                    if (SPLIT) Bl[r][c4 + q] = f2bf(v[q] - bf2f(h));
                }
            }
        }
        __syncthreads();

        bf16x8 a_h[2], b_h[2], a_l[2], b_l[2];
#pragma unroll
        for (int i = 0; i < 2; i++) {
            a_h[i] = *(const bf16x8*)&Ah[wr * 32 + i * 16 + lrow][lk * 8];
            b_h[i] = *(const bf16x8*)&Bh[wc * 32 + i * 16 + lrow][lk * 8];
            if (SPLIT) {
                a_l[i] = *(const bf16x8*)&Al[wr * 32 + i * 16 + lrow][lk * 8];
                b_l[i] = *(const bf16x8*)&Bl[wc * 32 + i * 16 + lrow][lk * 8];
            }
        }
#pragma unroll
        for (int i = 0; i < 2; i++)
#pragma unroll
            for (int j = 0; j < 2; j++) {
                acc[i][j] = __builtin_amdgcn_mfma_f32_16x16x32_bf16(a_h[i], b_h[j], acc[i][j], 0, 0, 0);
                if (SPLIT) {
                    acc[i][j] = __builtin_amdgcn_mfma_f32_16x16x32_bf16(a_h[i], b_l[j], acc[i][j], 0, 0, 0);
                    acc[i][j] = __builtin_amdgcn_mfma_f32_16x16x32_bf16(a_l[i], b_h[j], acc[i][j], 0, 0, 0);
                }
            }
    }

#pragma unroll
    for (int i = 0; i < 2; i++)
#pragma unroll
        for (int j = 0; j < 2; j++) {
            int n = n0 + wc * 32 + j * 16 + lrow;
            float bs = bias[n];
#pragma unroll
            for (int jj = 0; jj < 4; jj++) {
                int m = m0 + wr * 32 + i * 16 + lk * 4 + jj;
                if (m < M) {
                    float val = acc[i][j][jj] + bs;
                    if (C_BF16)
                        ((unsigned short*)Cv)[(size_t)batch * cBatch + (size_t)m * N + n] = f2bf(val);
                    else
                        ((float*)Cv)[(size_t)batch * cBatch + (size_t)m * N + n] = val;
                }
            }
        }
}

// ---------------- fused deformable attention ----------------
// block = (b,k): 512 threads, wave w = head h. Phase 0: lanes 0..23 compute
// the 24 points' bilinear weights + corner byte-offsets once into LDS.
// Phase 1: lane = (pt, kv, d2): 2 points in flight, each lane covers 2
// channels via uint loads. Logits via 4-step shfl reduce over 16 k-lanes.
__global__ __launch_bounds__(512) void attn_kernel(
    const float* __restrict__ q_proj, const float* __restrict__ pxy,
    const float* __restrict__ offs, const unsigned short* __restrict__ kv_t,
    float* __restrict__ S) {
    int bk = blockIdx.x;            // b*900 + k
    int b = bk / 900, k = bk % 900;
    int h = threadIdx.x >> 6;       // wave = head
    int lane = threadIdx.x & 63;

    __shared__ __align__(16) float        ldsW[8][24][4];
    __shared__ __align__(16) unsigned int ldsI[8][24][4];
    __shared__ float ldsL[8][24];

    if (lane < 24) {
        int cam = lane >> 2, p = lane & 3;
        int cid = cam * 7200 + bk;
        float px0 = pxy[cid * 2 + 0], px1 = pxy[cid * 2 + 1];
        float o0 = offs[(size_t)cid * 64 + (h * 4 + p) * 2 + 0];
        float o1 = offs[(size_t)cid * 64 + (h * 4 + p) * 2 + 1];
        float pc0 = px0 + o0 * (1.f / 32.f);
        float pc1 = px1 + o1 * (1.f / 88.f);
        float gx = 2.f * (pc0 * (1.f / 32.f)) - 1.f;
        float gy = 2.f * (pc1 * (1.f / 88.f)) - 1.f;
        float ix = (gx + 1.f) * 0.5f * 87.f;
        float iy = (gy + 1.f) * 0.5f * 31.f;
        float x0 = floorf(ix), y0 = floorf(iy), x1 = x0 + 1.f, y1 = y0 + 1.f;
        float wx1 = ix - x0, wx0 = x1 - ix, wy1 = iy - y0, wy0 = y1 - iy;
        float m00 = (x0 >= 0.f && x0 <= 87.f && y0 >= 0.f && y0 <= 31.f) ? 1.f : 0.f;
        float m01 = (x1 >= 0.f && x1 <= 87.f && y0 >= 0.f && y0 <= 31.f) ? 1.f : 0.f;
        float m10 = (x0 >= 0.f && x0 <= 87.f && y1 >= 0.f && y1 <= 31.f) ? 1.f : 0.f;
        float m11 = (x1 >= 0.f && x1 <= 87.f && y1 >= 0.f && y1 <= 31.f) ? 1.f : 0.f;
        int xi0 = (int)fminf(fmaxf(x0, 0.f), 87.f);
        int xi1 = (int)fminf(fmaxf(x1, 0.f), 87.f);
        int yi0 = (int)fminf(fmaxf(y0, 0.f), 31.f);
        int yi1 = (int)fminf(fmaxf(y1, 0.f), 31.f);
        unsigned int img = (unsigned int)(cam * 8 + b) * 2816u;
        ldsW[h][lane][0] = wx0 * wy0 * m00;
        ldsW[h][lane][1] = wx1 * wy0 * m01;
        ldsW[h][lane][2] = wx0 * wy1 * m10;
        ldsW[h][lane][3] = wx1 * wy1 * m11;
        ldsI[h][lane][0] = (img + yi0 * 88 + xi0) * 1024u;
        ldsI[h][lane][1] = (img + yi0 * 88 + xi1) * 1024u;
        ldsI[h][lane][2] = (img + yi1 * 88 + xi0) * 1024u;
        ldsI[h][lane][3] = (img + yi1 * 88 + xi1) * 1024u;
    }
    __syncthreads();

    const int d2 = lane & 15;               // channel pair
    const int pt = lane >> 5;               // point parity in flight
    const int chB = (((lane >> 4) & 1) * 256 + h * 32 + d2 * 2) * 2;  // byte offset
    const char* kvb = (const char*)kv_t;

    float q0 = q_proj[(size_t)bk * 256 + h * 32 + d2 * 2];
    float q1 = q_proj[(size_t)bk * 256 + h * 32 + d2 * 2 + 1];

    float vr0[12], vr1[12];
    const float inv_sqrt = 0.17677669529663687f;
#pragma unroll
    for (int lp = 0; lp < 12; lp++) {
        int l = lp * 2 + pt;
        f32x4 w = *(const f32x4*)ldsW[h][l];
        unsigned int i0 = ldsI[h][l][0], i1 = ldsI[h][l][1];
        unsigned int i2 = ldsI[h][l][2], i3 = ldsI[h][l][3];
        unsigned int u0 = *(const unsigned int*)(kvb + i0 + chB);
        unsigned int u1 = *(const unsigned int*)(kvb + i1 + chB);
        unsigned int u2 = *(const unsigned int*)(kvb + i2 + chB);
        unsigned int u3 = *(const unsigned int*)(kvb + i3 + chB);
        float a0 = w[0] * bf2f((unsigned short)u0) + w[1] * bf2f((unsigned short)u1)
                 + w[2] * bf2f((unsigned short)u2) + w[3] * bf2f((unsigned short)u3);
        float a1 = w[0] * bf2f((unsigned short)(u0 >> 16)) + w[1] * bf2f((unsigned short)(u1 >> 16))
                 + w[2] * bf2f((unsigned short)(u2 >> 16)) + w[3] * bf2f((unsigned short)(u3 >> 16));
        float t = q0 * a0 + q1 * a1;
        t += __shfl_xor(t, 1);
        t += __shfl_xor(t, 2);
        t += __shfl_xor(t, 4);
        t += __shfl_xor(t, 8);
        if ((lane & 31) == 0) ldsL[h][l] = t * inv_sqrt;
        vr0[lp] = a0; vr1[lp] = a1;
    }
    __syncthreads();

    float mx = -1e30f;
#pragma unroll
    for (int l = 0; l < 24; l++) mx = fmaxf(mx, ldsL[h][l]);
    float ssum = 0.f;
    float at12[12];
#pragma unroll
    for (int l = 0; l < 24; l++) {
        float e = __expf(ldsL[h][l] - mx);
        ssum += e;
        if ((l & 1) == 0) { if (pt == 0) at12[l >> 1] = e; }
        else              { if (pt == 1) at12[l >> 1] = e; }
    }
    float inv = 1.f / ssum;
    float o0 = 0.f, o1 = 0.f;
#pragma unroll
    for (int lp = 0; lp < 12; lp++) {
        float a = at12[lp] * inv;
        o0 += a * vr0[lp];
        o1 += a * vr1[lp];
    }
    o0 += __shfl_xor(o0, 32);
    o1 += __shfl_xor(o1, 32);
    if ((lane >> 4) == 1) {   // lanes 16..31: v-lanes, pt 0
        float2 ov; ov.x = o0; ov.y = o1;
        *(float2*)&S[(size_t)b * 230400 + (size_t)h * 28800 + k * 32 + d2 * 2] = ov;
    }
}

extern "C" void kernel_launch(void* const* d_in, const int* in_sizes, int n_in,
                              void* d_out, int out_size, void* d_ws, size_t ws_size,
                              hipStream_t stream) {
    const float* query    = (const float*)d_in[0];
    const float* points   = (const float*)d_in[1];
    const float* features = (const float*)d_in[2];
    const float* camM     = (const float*)d_in[3];
    const float* camb     = (const float*)d_in[4];
    const float* W_off    = (const float*)d_in[5];
    const float* b_off    = (const float*)d_in[6];
    const float* W_q      = (const float*)d_in[7];
    const float* b_q      = (const float*)d_in[8];
    const float* W_k      = (const float*)d_in[9];
    const float* b_k      = (const float*)d_in[10];
    const float* W_v      = (const float*)d_in[11];
    const float* b_v      = (const float*)d_in[12];
    const float* W_o      = (const float*)d_in[13];
    const float* b_o      = (const float*)d_in[14];

    char* ws = (char*)d_ws;
    unsigned short* feat_t = (unsigned short*)ws; ws += 69206016;   // [48][2816][256] bf16
    unsigned short* kv_t   = (unsigned short*)ws; ws += 138412032;  // [48][2816][512] bf16
    float* q_off  = (float*)ws; ws += 44236800;                     // [43200][256]
    float* offs   = (float*)ws; ws += 11059200;                     // [43200][64]
    float* pxy    = (float*)ws; ws += 345600;                       // [43200][2]
    float* q_proj = (float*)ws; ws += 7372800;                      // [7200][256]
    float* S      = (float*)ws; ws += 7372800;                      // [8][230400] scrambled
    unsigned short* Wkv = (unsigned short*)ws; ws += 524288;        // [512][256] bf16
    float* bkv    = (float*)ws; ws += 2048;                         // [512]

    prep_wkv<<<512, 256, 0, stream>>>(W_k, b_k, W_v, b_v, Wkv, bkv);
    transpose_feat<<<dim3(88, 8, 48), 256, 0, stream>>>(features, feat_t);
    camf_kernel<<<43200, 256, 0, stream>>>(query, points, feat_t, camM, camb, q_off, pxy);
    // offsets = q_off @ W_off^T + b_off : [43200 x 64]
    gemm_bf16<true, false><<<dim3(675, 1, 1), 256, 0, stream>>>(
        q_off, 0, W_off, b_off, offs, 0, 43200, 64, 256, 256);
    // kv_t = feat_t @ Wkv^T + bkv : one flat GEMM [135168 x 512], bf16 out
    gemm_kv<<<dim3(1056, 4), 256, 0, stream>>>(feat_t, Wkv, bkv, kv_t);
    // q_proj = query @ W_q^T + b_q : [7200 x 256]
    gemm_bf16<true, false><<<dim3(113, 4, 1), 256, 0, stream>>>(
        query, 0, W_q, b_q, q_proj, 0, 7200, 256, 256, 256);
    attn_kernel<<<7200, 512, 0, stream>>>(q_proj, pxy, offs, kv_t, S);
    // out = S @ W_o^T + b_o : [7200 x 256]
    gemm_bf16<true, false><<<dim3(113, 4, 1), 256, 0, stream>>>(
        S, 0, W_o, b_o, d_out, 0, 7200, 256, 256, 256);
}